// Round 2
// 309.292 us; speedup vs baseline: 1.1449x; 1.1449x over previous
//
#include <hip/hip_runtime.h>
#include <math.h>

#define B_SZ 16
#define D_CH 512
#define U_LEN 2048
#define R_LEN 512
#define T_LEN 2560
#define KS 31
#define CS 30

typedef __attribute__((ext_vector_type(8))) short short8;
typedef __attribute__((ext_vector_type(4))) float floatx4;

__device__ __forceinline__ float bf2f(ushort u) {
    unsigned v = (unsigned)u << 16;
    float f; __builtin_memcpy(&f, &v, 4); return f;
}
__device__ __forceinline__ ushort f2bf(float f) {
    unsigned v; __builtin_memcpy(&v, &f, 4);
    v += 0x7fff + ((v >> 16) & 1);
    return (ushort)(v >> 16);
}
__device__ __forceinline__ float sigmoidf_(float x) { return 1.0f / (1.0f + __expf(-x)); }

__device__ __forceinline__ void gld16(const void* g, void* l) {
    __builtin_amdgcn_global_load_lds((const __attribute__((address_space(1))) void*)g,
                                     (__attribute__((address_space(3))) void*)l, 16, 0, 0);
}

// ---- conversion kernel: xb (T,B,D) bf16, weights bf16 (w1 row-interleaved), cache bf16 ----
// w1 permute: rows' [32m..32m+15] = a-rows n=16m.. ; rows' [32m+16..32m+31] = g-rows 512+16m..
// -> in k1, a B-tile col-group fc even holds 'a', fc odd holds the matching 'g' for the SAME
//    output col n = lane-local GLU, no shuffles.
__global__ __launch_bounds__(256) void k_conv_all(
    const float* __restrict__ utt, const float* __restrict__ rc, const float* __restrict__ cache,
    const float* __restrict__ w1, const float* __restrict__ w2,
    ushort* __restrict__ xb, ushort* __restrict__ w1b, ushort* __restrict__ w2b,
    ushort* __restrict__ xc)
{
    int blk = blockIdx.x;
    if (blk < 5120) {
        size_t f4 = (size_t)blk * 1024 + threadIdx.x * 4;
        size_t o = f4 * 4;
        int q = (int)(o >> 9), d = (int)(o & 511);
        const float* src = (q < 8192) ? rc + ((size_t)q << 9) + d
                                      : utt + (((size_t)(q - 8192)) << 9) + d;
        ushort* dst = xb + o;
        #pragma unroll
        for (int i = 0; i < 4; ++i) {
            float4 v = ((const float4*)src)[i];
            ushort4 u4; u4.x = f2bf(v.x); u4.y = f2bf(v.y); u4.z = f2bf(v.z); u4.w = f2bf(v.w);
            ((ushort4*)dst)[i] = u4;
        }
    } else if (blk < 5312) {
        int t = (blk - 5120) * 1024 + threadIdx.x * 4;
        if (t < 131072) {
            // w1 with 16-row a/g interleave
            #pragma unroll
            for (int i = 0; i < 4; ++i) {
                int e = (t + i) << 2;           // element index into [1024][512]
                int row = e >> 9, k = e & 511;
                int rr = row & 511;
                int rp = (rr >> 4) * 32 + ((row >> 9) << 4) + (rr & 15);
                float4 v = ((const float4*)w1)[t + i];
                ushort4 u4; u4.x = f2bf(v.x); u4.y = f2bf(v.y); u4.z = f2bf(v.z); u4.w = f2bf(v.w);
                ((ushort4*)w1b)[rp * 128 + (k >> 2)] = u4;
            }
        } else {
            int t2 = t - 131072;
            #pragma unroll
            for (int i = 0; i < 4; ++i) {
                float4 v = ((const float4*)w2)[t2 + i];
                ushort4 u4; u4.x = f2bf(v.x); u4.y = f2bf(v.y); u4.z = f2bf(v.z); u4.w = f2bf(v.w);
                ((ushort4*)w2b)[t2 + i] = u4;
            }
        }
    } else {
        int o = (blk - 5312) * 256 + threadIdx.x;
        int d = o & 511, p = o >> 13, b = (o >> 9) & 15;
        xc[o] = f2bf(cache[((size_t)b * D_CH + d) * CS + p]);
    }
}

// ---- K1: depth-3 counted-vmcnt pipelined MFMA GEMM (xb @ w1p^T) + GLU -> y bf16 ----
// 128x128 tile, BK=32, 4 waves (64x64/wave), 4 LDS buffers (64KB) -> 2 blocks/CU.
// Schedule: prologue stages tiles 0..2; step s: vmcnt(8)+s_barrier (counted, never 0
// until tail) -> stage tile s+3 -> ds_read swizzled frags -> setprio(1) 16 MFMA.
// T2 chunk-XOR swizzle (q ^= (row>>1)&3) applied on global SOURCE addr (gld16 dest
// linear) and on read addr -> conflict-free ds_read_b128.
// XCD swizzle: all 8 n-sharers of an A-panel land on one XCD.
__global__ __launch_bounds__(256, 2) void k1_mfma(
    const ushort* __restrict__ xb, const ushort* __restrict__ w1p,
    const float* __restrict__ b1, ushort* __restrict__ y)
{
    __shared__ __attribute__((aligned(16))) ushort lds[4][2][4096];
    const int tid = threadIdx.x;
    const int w = tid >> 6, lane = tid & 63;
    const int col = lane & 15, quad = lane >> 4;
    const int wm = w >> 1, wn = w & 1;
    const int bid = blockIdx.x;
    const int f = (bid & 7) * 320 + (bid >> 3);
    const int mt = f >> 3, nn = f & 7;
    const int q0 = mt * 128, n0 = nn * 128;

    floatx4 acc[4][4];
    #pragma unroll
    for (int i = 0; i < 4; ++i)
        #pragma unroll
        for (int j = 0; j < 4; ++j) acc[i][j] = 0.f;

    // fragment read byte-offsets within an 8KB tile (row*64B, chunk XOR-swizzled)
    int offA[4], offB[4];
    #pragma unroll
    for (int i = 0; i < 4; ++i) {
        int rA = wm * 64 + i * 16 + col;
        offA[i] = rA * 64 + ((quad ^ ((rA >> 1) & 3)) << 4);
        int rB = wn * 64 + i * 16 + col;
        offB[i] = rB * 64 + ((quad ^ ((rB >> 1) & 3)) << 4);
    }

    // staging: thread stages rows srow and 64+srow, 16B chunk sq, source pre-swizzled
    const int srow = tid >> 2;
    const int sqs = (tid & 3) ^ ((srow >> 1) & 3);   // same for srow and 64+srow
    const ushort* gA0 = xb  + (((size_t)(q0 + srow))      << 9) + (sqs << 3);
    const ushort* gA1 = xb  + (((size_t)(q0 + 64 + srow)) << 9) + (sqs << 3);
    const ushort* gB0 = w1p + (((size_t)(n0 + srow))      << 9) + (sqs << 3);
    const ushort* gB1 = w1p + (((size_t)(n0 + 64 + srow)) << 9) + (sqs << 3);

#define STAGE1(t_, bi_) do { \
        const int kc_ = (t_) << 5; \
        gld16(gA0 + kc_, &lds[bi_][0][w * 512]); \
        gld16(gA1 + kc_, &lds[bi_][0][2048 + w * 512]); \
        gld16(gB0 + kc_, &lds[bi_][1][w * 512]); \
        gld16(gB1 + kc_, &lds[bi_][1][2048 + w * 512]); \
    } while (0)

    STAGE1(0, 0); STAGE1(1, 1); STAGE1(2, 2);

    #pragma unroll
    for (int s = 0; s < 16; ++s) {
        if (s < 14)       asm volatile("s_waitcnt vmcnt(8)\n\ts_barrier" ::: "memory");
        else if (s == 14) asm volatile("s_waitcnt vmcnt(4)\n\ts_barrier" ::: "memory");
        else              asm volatile("s_waitcnt vmcnt(0)\n\ts_barrier" ::: "memory");
        if (s < 13) STAGE1(s + 3, (s + 3) & 3);
        const char* A  = (const char*)&lds[s & 3][0][0];
        const char* Bp = (const char*)&lds[s & 3][1][0];
        short8 af[4], bf8[4];
        #pragma unroll
        for (int i = 0; i < 4; ++i) af[i]  = *(const short8*)(A + offA[i]);
        #pragma unroll
        for (int j = 0; j < 4; ++j) bf8[j] = *(const short8*)(Bp + offB[j]);
        __builtin_amdgcn_s_setprio(1);
        #pragma unroll
        for (int i = 0; i < 4; ++i)
            #pragma unroll
            for (int j = 0; j < 4; ++j)
                acc[i][j] = __builtin_amdgcn_mfma_f32_16x16x32_bf16(af[i], bf8[j], acc[i][j], 0, 0, 0);
        __builtin_amdgcn_s_setprio(0);
    }
#undef STAGE1

    // GLU epilogue: fc even = a, fc odd = g (same output col n, same lane)
    const int nb2 = (n0 + wn * 64) >> 1;
    #pragma unroll
    for (int fe = 0; fe < 2; ++fe) {
        const int na = nb2 + fe * 16 + col;
        const float ba = b1[na], bg = b1[512 + na];
        #pragma unroll
        for (int i = 0; i < 4; ++i) {
            const int row = q0 + wm * 64 + i * 16 + quad * 4;
            #pragma unroll
            for (int r = 0; r < 4; ++r) {
                float a = acc[i][2 * fe][r] + ba;
                float g = acc[i][2 * fe + 1][r] + bg;
                y[(((size_t)(row + r)) << 9) + na] = f2bf(a * sigmoidf_(g));
            }
        }
    }
}

// ---- K2 fused: depthwise conv (utt path + rc path) + swish -> zb; emits new_cache ----
__global__ __launch_bounds__(256) void k2_fused(
    const ushort* __restrict__ y, const ushort* __restrict__ xc,
    const float* __restrict__ wd, const float* __restrict__ bd,
    ushort* __restrict__ z, float* __restrict__ out)
{
    __shared__ __attribute__((aligned(16))) char smem[20352];
    const int tid = threadIdx.x;
    int g = blockIdx.x;

    if (g < 4096) {
        ushort* sy = (ushort*)smem;            // 64*97
        float*  sw = (float*)(smem + 12416);   // 64*31
        const int u0 = (g & 31) * 64;
        const int d0 = ((g >> 5) & 7) * 64;
        const int b  = g >> 8;

        for (int idx = tid; idx < 94 * 8; idx += 256) {
            int r  = idx >> 3;
            int c8 = idx & 7;
            int p  = u0 + r;
            int dg = d0 + c8 * 8;
            const ushort* src = (p < CS) ? xc + (((size_t)(p * 16 + b)) << 9) + dg
                                         : y  + (((size_t)((482 + p) * 16 + b)) << 9) + dg;
            ushort tmp[8];
            *(int4*)tmp = *(const int4*)src;
            #pragma unroll
            for (int j = 0; j < 8; ++j) sy[(c8 * 8 + j) * 97 + r] = tmp[j];
        }
        for (int idx = tid; idx < 64 * 31; idx += 256) {
            int d = idx / 31, k = idx - d * 31;
            sw[d * 31 + k] = wd[(size_t)(d0 + d) * KS + k];
        }
        __syncthreads();

        const int dl   = tid & 63;
        const int useg = (tid >> 6) * 16;
        float win[46];
        #pragma unroll
        for (int p = 0; p < 46; ++p) win[p] = bf2f(sy[dl * 97 + useg + p]);
        float bias = bd[d0 + dl];
        float acc[16];
        #pragma unroll
        for (int i = 0; i < 16; ++i) acc[i] = bias;
        for (int k = 0; k < 31; ++k) {
            float w = sw[dl * 31 + k];
            #pragma unroll
            for (int i = 0; i < 16; ++i) acc[i] = fmaf(w, win[k + i], acc[i]);
        }
        #pragma unroll
        for (int i = 0; i < 16; ++i) {
            float v = acc[i];
            v = v * sigmoidf_(v - 1.0f);
            int u = u0 + useg + i;
            z[(((size_t)((R_LEN + u) * 16 + b)) << 9) + d0 + dl] = f2bf(v);
        }
        if ((g & 31) == 31) {
            for (int idx = tid; idx < 64 * 30; idx += 256) {
                int dl2 = idx & 63, j = idx >> 6;
                out[(size_t)20971520 + ((size_t)b * D_CH + d0 + dl2) * CS + j] = bf2f(sy[dl2 * 97 + 64 + j]);
            }
        }
    } else {
        g -= 4096;
        ushort* sy = (ushort*)smem;            // 38*256
        const int i  = g & 63;
        const int b  = (g >> 6) & 15;
        const int dbase = (g >> 10) * 256;

        for (int idx = tid; idx < 38 * 32; idx += 256) {
            int r  = idx >> 5;
            int c8 = idx & 31;
            int t = (r < CS) ? (R_LEN + 32 * i + 2 + r) : (8 * i + (r - CS));
            *(int4*)&sy[r * 256 + c8 * 8] =
                *(const int4*)(y + (((size_t)(t * 16 + b)) << 9) + dbase + c8 * 8);
        }
        __syncthreads();

        const int dd = dbase + tid;
        float wr[31];
        #pragma unroll
        for (int k = 0; k < 31; ++k) wr[k] = wd[(size_t)dd * KS + k];
        float bias = bd[dd];
        #pragma unroll
        for (int j = 0; j < 8; ++j) {
            float acc = bias;
            #pragma unroll
            for (int k = 0; k < 31; ++k) acc = fmaf(wr[k], bf2f(sy[(j + k) * 256 + tid]), acc);
            float v = acc * sigmoidf_(acc - 1.0f);
            z[(((size_t)((i * 8 + j) * 16 + b)) << 9) + dd] = f2bf(v);
        }
    }
}

// ---- K3: same depth-3 pipelined GEMM (zb @ w2b^T) + bias -> final fp32 ----
__global__ __launch_bounds__(256, 2) void k3_mfma(
    const ushort* __restrict__ zb, const ushort* __restrict__ w2b,
    const float* __restrict__ b2, float* __restrict__ out)
{
    __shared__ __attribute__((aligned(16))) ushort lds[4][2][4096];
    const int tid = threadIdx.x;
    const int w = tid >> 6, lane = tid & 63;
    const int col = lane & 15, quad = lane >> 4;
    const int wm = w >> 1, wn = w & 1;
    const int bid = blockIdx.x;
    const int f = (bid & 7) * 160 + (bid >> 3);
    const int mt = f >> 2, nn = f & 3;
    const int q0 = mt * 128, n0 = nn * 128;

    floatx4 acc[4][4];
    #pragma unroll
    for (int i = 0; i < 4; ++i)
        #pragma unroll
        for (int j = 0; j < 4; ++j) acc[i][j] = 0.f;

    int offA[4], offB[4];
    #pragma unroll
    for (int i = 0; i < 4; ++i) {
        int rA = wm * 64 + i * 16 + col;
        offA[i] = rA * 64 + ((quad ^ ((rA >> 1) & 3)) << 4);
        int rB = wn * 64 + i * 16 + col;
        offB[i] = rB * 64 + ((quad ^ ((rB >> 1) & 3)) << 4);
    }

    const int srow = tid >> 2;
    const int sqs = (tid & 3) ^ ((srow >> 1) & 3);
    const ushort* gA0 = zb  + (((size_t)(q0 + srow))      << 9) + (sqs << 3);
    const ushort* gA1 = zb  + (((size_t)(q0 + 64 + srow)) << 9) + (sqs << 3);
    const ushort* gB0 = w2b + (((size_t)(n0 + srow))      << 9) + (sqs << 3);
    const ushort* gB1 = w2b + (((size_t)(n0 + 64 + srow)) << 9) + (sqs << 3);

#define STAGE3(t_, bi_) do { \
        const int kc_ = (t_) << 5; \
        gld16(gA0 + kc_, &lds[bi_][0][w * 512]); \
        gld16(gA1 + kc_, &lds[bi_][0][2048 + w * 512]); \
        gld16(gB0 + kc_, &lds[bi_][1][w * 512]); \
        gld16(gB1 + kc_, &lds[bi_][1][2048 + w * 512]); \
    } while (0)

    STAGE3(0, 0); STAGE3(1, 1); STAGE3(2, 2);

    #pragma unroll
    for (int s = 0; s < 16; ++s) {
        if (s < 14)       asm volatile("s_waitcnt vmcnt(8)\n\ts_barrier" ::: "memory");
        else if (s == 14) asm volatile("s_waitcnt vmcnt(4)\n\ts_barrier" ::: "memory");
        else              asm volatile("s_waitcnt vmcnt(0)\n\ts_barrier" ::: "memory");
        if (s < 13) STAGE3(s + 3, (s + 3) & 3);
        const char* A  = (const char*)&lds[s & 3][0][0];
        const char* Bp = (const char*)&lds[s & 3][1][0];
        short8 af[4], bf8[4];
        #pragma unroll
        for (int i = 0; i < 4; ++i) af[i]  = *(const short8*)(A + offA[i]);
        #pragma unroll
        for (int j = 0; j < 4; ++j) bf8[j] = *(const short8*)(Bp + offB[j]);
        __builtin_amdgcn_s_setprio(1);
        #pragma unroll
        for (int i = 0; i < 4; ++i)
            #pragma unroll
            for (int j = 0; j < 4; ++j)
                acc[i][j] = __builtin_amdgcn_mfma_f32_16x16x32_bf16(af[i], bf8[j], acc[i][j], 0, 0, 0);
        __builtin_amdgcn_s_setprio(0);
    }
#undef STAGE3

    #pragma unroll
    for (int j = 0; j < 4; ++j) {
        const int n = n0 + wn * 64 + j * 16 + col;
        const float bb = b2[n];
        #pragma unroll
        for (int i = 0; i < 4; ++i) {
            const int qrow = q0 + wm * 64 + i * 16 + quad * 4;
            #pragma unroll
            for (int r = 0; r < 4; ++r) {
                const int q = qrow + r;
                float v = acc[i][j][r] + bb;
                size_t off = (q < 8192) ? (size_t)16777216 + ((size_t)q << 9)
                                        : ((size_t)(q - 8192) << 9);
                out[off + n] = v;
            }
        }
    }
}

extern "C" void kernel_launch(void* const* d_in, const int* in_sizes, int n_in,
                              void* d_out, int out_size, void* d_ws, size_t ws_size,
                              hipStream_t stream)
{
    const float* utt   = (const float*)d_in[0];
    const float* rc    = (const float*)d_in[1];
    const float* cache = (const float*)d_in[2];
    const float* w1    = (const float*)d_in[3];
    const float* b1    = (const float*)d_in[4];
    const float* wd    = (const float*)d_in[5];
    const float* bd    = (const float*)d_in[6];
    const float* w2    = (const float*)d_in[7];
    const float* b2    = (const float*)d_in[8];
    float* out = (float*)d_out;

    ushort* xb  = (ushort*)d_ws;                 // (T,B,D) bf16, rows q=t*16+b
    ushort* y   = xb  + (size_t)20971520;
    ushort* zb  = y   + (size_t)20971520;
    ushort* w1b = zb  + (size_t)20971520;        // w1 bf16, 16-row a/g interleaved
    ushort* w2b = w1b + (size_t)524288;
    ushort* xc  = w2b + (size_t)262144;          // (CS,B,D) bf16

    k_conv_all<<<dim3(6272), 256, 0, stream>>>(utt, rc, cache, w1, w2, xb, w1b, w2b, xc);
    k1_mfma   <<<dim3(2560), 256, 0, stream>>>(xb, w1b, b1, y);
    k2_fused  <<<dim3(6144), 256, 0, stream>>>(y, xc, wd, bd, zb, out);
    k3_mfma   <<<dim3(1280), 256, 0, stream>>>(zb, w2b, b2, out);
}